// Round 7
// baseline (228.599 us; speedup 1.0000x reference)
//
#include <hip/hip_runtime.h>

#define LOG2E 1.44269504088896340736f

typedef __attribute__((ext_vector_type(8))) short short8;
typedef __attribute__((ext_vector_type(4))) float float4v;
typedef __attribute__((ext_vector_type(2))) float float2v;
typedef __attribute__((ext_vector_type(2))) int int2v;

__device__ inline unsigned short f2bf(float f) {
    union { float f; unsigned u; } v; v.f = f;
    unsigned r = v.u + 0x7fffu + ((v.u >> 16) & 1u);
    return (unsigned short)(r >> 16);
}
__device__ inline float bf2f(unsigned short u) {
    union { unsigned u; float f; } v; v.u = ((unsigned)u) << 16;
    return v.f;
}
// pack hi16(a)|hi16(b)<<16 with +0x8000 rounding (2 adds + 1 perm)
__device__ inline unsigned pk_bf16(float a, float b) {
    union { float f; unsigned u; } ua, ub; ua.f = a; ub.f = b;
    return __builtin_amdgcn_perm(ub.u + 0x8000u, ua.u + 0x8000u, 0x07060302u);
}

// ---------------------------------------------------------------------------
// Kernel 0: convert weights to bf16, concatenated Wbf[320][256]
// rows 0-31 = wq, 32-63 = wk, 64-319 = wv.  grid 80 x 256.
// ---------------------------------------------------------------------------
__global__ void wcvt_kernel(const float* __restrict__ wq, const float* __restrict__ wk,
                            const float* __restrict__ wv, unsigned short* __restrict__ Wbf)
{
    int idx = blockIdx.x * 256 + threadIdx.x;     // 20480 float4s
    int e4  = idx * 4;
    int row = e4 >> 8, col = e4 & 255;
    const float* src = (row < 32) ? (wq + row * 256 + col)
                     : (row < 64) ? (wk + (row - 32) * 256 + col)
                                  : (wv + (row - 64) * 256 + col);
    float4v v = *(const float4v*)src;
    int2v p;
    p.x = (unsigned)f2bf(v[0]) | ((unsigned)f2bf(v[1]) << 16);
    p.y = (unsigned)f2bf(v[2]) | ((unsigned)f2bf(v[3]) << 16);
    *(int2v*)(Wbf + e4) = p;
}

// ---------------------------------------------------------------------------
// Kernel 1: projections.  16-pixel i-tiles, grid 1024 (b = blk&3), block 256.
// Q stored (N,32) bf16 PRE-SCALED by cd[i]*log2(e)  (fixed-max softmax fold).
// K stored (N,32) bf16.
// V stored [b][jblk=i>>5][c][p] bf16, p = ((j&15)>>2)*8 + (j>>4)*4 + (j&3)
// — the k-order of attn's PV MFMA A-fragment (verified R5/R6: passed).
// This round: staging split into 2 low-pressure passes; kc loop unroll
// capped at 2 — defends against VGPR spill (suspected hidden proj cost).
// ---------------------------------------------------------------------------
__launch_bounds__(256, 3)
__global__ void proj_kernel(const float* __restrict__ a_p, const float* __restrict__ b_p,
                            const float* __restrict__ c_p,
                            const float* __restrict__ bq, const float* __restrict__ bk,
                            const float* __restrict__ bv,
                            const unsigned short* __restrict__ Wbf,
                            unsigned short* __restrict__ Qg, unsigned short* __restrict__ Kg,
                            unsigned short* __restrict__ Vg)
{
    __shared__ unsigned At[16 * 132];   // a-tile transposed (i, c-pairs) bf16x2
    __shared__ unsigned Bt[16 * 132];

    const int t    = threadIdx.x;
    const int blk  = blockIdx.x;
    const int b    = blk & 3;
    const int t16  = blk >> 2;
    const int i0   = t16 * 16;
    const int lane = t & 63;
    const int w    = t >> 6;
    const int q    = lane >> 4;
    const int n    = lane & 15;

    // ---- stage: 2 c-rows per thread, two half-passes (16 live regs max) ----
    {
        int arr = t >> 7, p = t & 127;
        const float* src = (arr ? b_p : a_p) + ((size_t)(b * 256 + 2 * p)) * 4096 + i0;
        unsigned* dst = (arr ? Bt : At) + p;
#pragma unroll
        for (int h = 0; h < 2; ++h) {
            float4v r0a = *(const float4v*)(src + h * 8);
            float4v r0b = *(const float4v*)(src + h * 8 + 4);
            float4v r1a = *(const float4v*)(src + 4096 + h * 8);
            float4v r1b = *(const float4v*)(src + 4096 + h * 8 + 4);
#pragma unroll
            for (int jj = 0; jj < 4; ++jj)
                dst[(h * 8 + jj) * 132] = (unsigned)f2bf(r0a[jj]) | ((unsigned)f2bf(r1a[jj]) << 16);
#pragma unroll
            for (int jj = 0; jj < 4; ++jj)
                dst[(h * 8 + 4 + jj) * 132] = (unsigned)f2bf(r0b[jj]) | ((unsigned)f2bf(r1b[jj]) << 16);
        }
    }
    __syncthreads();

    // ---- GEMM: wave w owns m-tiles {w, w+4, w+8, w+12, w+16} (rows of Wbf) ----
    float4v acc[5];
#pragma unroll
    for (int kk = 0; kk < 5; ++kk) acc[kk] = (float4v){0.f, 0.f, 0.f, 0.f};

#pragma unroll 2
    for (int kc = 0; kc < 8; ++kc) {
        short8 atf = *(const short8*)((const unsigned short*)At + n * 264 + kc * 32 + q * 8);
        short8 btf = atf;
        if (w >= 2)  // only waves 2,3 own a K m-tile
            btf = *(const short8*)((const unsigned short*)Bt + n * 264 + kc * 32 + q * 8);
#pragma unroll
        for (int kk = 0; kk < 5; ++kk) {
            int mt = w + 4 * kk;
            short8 wf = *(const short8*)(Wbf + (size_t)(mt * 16 + n) * 256 + kc * 32 + q * 8);
            short8 bsel = (mt == 2 || mt == 3) ? btf : atf;
            acc[kk] = __builtin_amdgcn_mfma_f32_16x16x32_bf16(wf, bsel, acc[kk], 0, 0, 0);
        }
    }

    // ---- store (C-layout: row m = mt*16+q*4+r, col i = i0+n) ----
    const int i = i0 + n;
    const int jj = i & 31;
    const int pperm = ((jj & 15) >> 2) * 8 + (jj >> 4) * 4 + (jj & 3);
    // cd for this pixel (down-sampled c), pre-multiplied by log2(e): folded into Q
    const float cdq = c_p[b * 16384 + (i >> 6) * 256 + (i & 63) * 2] * LOG2E;
#pragma unroll
    for (int kk = 0; kk < 5; ++kk) {
        int mt = w + 4 * kk;
#pragma unroll
        for (int r = 0; r < 4; ++r) {
            int mm = mt * 16 + q * 4 + r;
            float bias = (mm < 32) ? bq[mm] : (mm < 64) ? bk[mm - 32] : bv[mm - 64];
            float val = acc[kk][r] + bias;
            if (mm < 32) {
                Qg[(size_t)(b * 4096 + i) * 32 + mm] = f2bf(val * cdq);
            } else if (mm < 64) {
                Kg[(size_t)(b * 4096 + i) * 32 + (mm - 32)] = f2bf(val);
            } else {
                Vg[(size_t)(((b * 128 + (i >> 5)) * 256) + (mm - 64)) * 32 + pperm] = f2bf(val);
            }
        }
    }
}

// ---------------------------------------------------------------------------
// Kernel 2: flash attention, split-j, fixed-max softmax.  NO LDS, NO barriers.
// grid 1024: b=blk&3, rt=(blk>>2)&63, s=blk>>8.  Block 256 = 4 waves.
// 2x2 SPLIT: wave w = (rh=w&1, ch=w>>1) owns rows [32rh,32rh+32) x channels
// [128ch,128ch+128).  S redundancy 2x (vs R6's 4x — halves exp2/pack VALU,
// which was the R6 bottleneck: VALUBusy 51% > MfmaUtil 29%); V reads 2x
// redundant (8 KB/iter/wave — half of R5's pathological level).
// S^T trick: MFMA(A=K,B=Q) C-layout output IS the PV A-fragment (lane col
// n = row i); V's j-permutation supplies matching k-order.
// p = exp2(QK - 16); l via per-lane sums + 2 shuffles at epilogue.
// ---------------------------------------------------------------------------
__launch_bounds__(256, 3)
__global__ void attn_kernel(const unsigned short* __restrict__ Qg,
                            const unsigned short* __restrict__ Kg,
                            const unsigned short* __restrict__ Vg,
                            unsigned short* __restrict__ Opart, float* __restrict__ lsum)
{
    const int t    = threadIdx.x;
    const int blk  = blockIdx.x;
    const int b    = blk & 3;
    const int rt   = (blk >> 2) & 63;
    const int s    = blk >> 8;
    const int i0   = rt * 64;
    const int lane = t & 63;
    const int w    = t >> 6;
    const int rh   = w & 1;
    const int ch   = w >> 1;
    const int q    = lane >> 4;
    const int n    = lane & 15;

    // Q B-frags for my 2 row-tiles (rows i0 + rh*32 + ig*16 + n)
    short8 qf[2];
#pragma unroll
    for (int ig = 0; ig < 2; ++ig)
        qf[ig] = *(const short8*)(Qg + (size_t)(b * 4096 + i0 + rh * 32 + ig * 16 + n) * 32 + q * 8);

    float4v acc[2][8];   // [ig][ct]
#pragma unroll
    for (int ig = 0; ig < 2; ++ig)
#pragma unroll
        for (int ct = 0; ct < 8; ++ct) acc[ig][ct] = (float4v){0.f, 0.f, 0.f, 0.f};
    float lsc[2] = {0.f, 0.f};

    const float4v m16v = (float4v){-16.f, -16.f, -16.f, -16.f};

    const unsigned short* kb = Kg + (size_t)(b * 4096 + s * 1024 + n) * 32 + q * 8;
    // my 128-c V slice: [b][jblk][c][p], c = 128ch + ct*16 + n, p = q*8..+8
    const unsigned short* vb = Vg + ((size_t)((b * 128 + s * 32) * 256 + ch * 128 + n)) * 32 + q * 8;

    short8 kf0 = *(const short8*)(kb);
    short8 kf1 = *(const short8*)(kb + 512);

#pragma unroll 1
    for (int it = 0; it < 32; ++it) {
        // V for this iter (8 KB/wave) — issued a full S-phase ahead of use
        short8 vf[8];
#pragma unroll
        for (int ct = 0; ct < 8; ++ct)
            vf[ct] = *(const short8*)(vb + ct * 512);

        // S^T + exp2 + pack, per row-tile
        short8 pf[2];
#pragma unroll
        for (int ig = 0; ig < 2; ++ig) {
            float4v s0 = __builtin_amdgcn_mfma_f32_16x16x32_bf16(kf0, qf[ig], m16v, 0, 0, 0);
            float4v s1 = __builtin_amdgcn_mfma_f32_16x16x32_bf16(kf1, qf[ig], m16v, 0, 0, 0);
            float p0 = __builtin_amdgcn_exp2f(s0[0]), p1 = __builtin_amdgcn_exp2f(s0[1]);
            float p2 = __builtin_amdgcn_exp2f(s0[2]), p3 = __builtin_amdgcn_exp2f(s0[3]);
            float p4 = __builtin_amdgcn_exp2f(s1[0]), p5 = __builtin_amdgcn_exp2f(s1[1]);
            float p6 = __builtin_amdgcn_exp2f(s1[2]), p7 = __builtin_amdgcn_exp2f(s1[3]);
            lsc[ig] += ((p0 + p1) + (p2 + p3)) + ((p4 + p5) + (p6 + p7));
            union { short8 s8; unsigned u[4]; } pf_;
            pf_.u[0] = pk_bf16(p0, p1);   // k = jt*4 + r order (matches V perm)
            pf_.u[1] = pk_bf16(p2, p3);
            pf_.u[2] = pk_bf16(p4, p5);
            pf_.u[3] = pk_bf16(p6, p7);
            pf[ig] = pf_.s8;
        }

        // prefetch next iter's K while PV MFMAs run (last iter reads into Vg:
        // in-bounds workspace, unused)
        kf0 = *(const short8*)(kb + 1024);
        kf1 = *(const short8*)(kb + 1536);

#pragma unroll
        for (int ig = 0; ig < 2; ++ig)
#pragma unroll
            for (int ct = 0; ct < 8; ++ct)
                acc[ig][ct] = __builtin_amdgcn_mfma_f32_16x16x32_bf16(pf[ig], vf[ct], acc[ig][ct], 0, 0, 0);

        kb += 1024;    // 32 j-rows * 32
        vb += 8192;    // next jblk: 256 c * 32
    }

    // ---- epilogue: O partial (bf16, unnormalized) + l per row ----
    const size_t obase = (size_t)blk * 16384;
#pragma unroll
    for (int ig = 0; ig < 2; ++ig)
#pragma unroll
        for (int ct = 0; ct < 8; ++ct) {
            int c = ch * 128 + ct * 16 + n;
            int i = rh * 32 + ig * 16 + q * 4;
            int2v pk;
            pk.x = (int)pk_bf16(acc[ig][ct][0], acc[ig][ct][1]);
            pk.y = (int)pk_bf16(acc[ig][ct][2], acc[ig][ct][3]);
            *(int2v*)(Opart + obase + (size_t)c * 64 + i) = pk;
        }
    // row sums: reduce over the 4 q-lanes; ch==0 waves store their row-half
#pragma unroll
    for (int ig = 0; ig < 2; ++ig) {
        float v = lsc[ig];
        v += __shfl_xor(v, 16, 64);
        v += __shfl_xor(v, 32, 64);
        if (ch == 0 && lane < 16)
            lsum[(size_t)blk * 64 + rh * 32 + ig * 16 + lane] = v;
    }
}

// ---------------------------------------------------------------------------
// Kernel 3: combine 4 splits + residual.  grid 2048: b=blk&3, rt=(blk>>2)&63,
// cs=blk>>8 (8 c-slices of 32).  out = gam*a*cd + (1-cd) * (sum_s O_s)/(sum_s l_s)
// ---------------------------------------------------------------------------
__launch_bounds__(256, 4)
__global__ void combine_kernel(const float* __restrict__ a_p, const float* __restrict__ c_p,
                               const float* __restrict__ gamma_p,
                               const unsigned short* __restrict__ Opart,
                               const float* __restrict__ lsum, float* __restrict__ out)
{
    __shared__ float invL[64];
    __shared__ float cdl[64];

    const int t   = threadIdx.x;
    const int blk = blockIdx.x;
    const int b   = blk & 3;
    const int rt  = (blk >> 2) & 63;
    const int cs  = blk >> 8;
    const int i0  = rt * 64;

    if (t < 64) {
        float L = 0.f;
#pragma unroll
        for (int s = 0; s < 4; ++s)
            L += lsum[(size_t)((s << 8) | (rt << 2) | b) * 64 + t];
        invL[t] = 1.0f / L;
        cdl[t] = c_p[b * 16384 + rt * 256 + 2 * t];
    }
    __syncthreads();

    const float gam = gamma_p[0];
    const int il = (t & 31) * 2;
    const int cq = t >> 5;
#pragma unroll
    for (int k = 0; k < 4; ++k) {
        int c = cs * 32 + cq + 8 * k;
        float o0 = 0.f, o1 = 0.f;
#pragma unroll
        for (int s = 0; s < 4; ++s) {
            int idx = (s << 8) | (rt << 2) | b;
            unsigned pr = *(const unsigned*)(Opart + (size_t)idx * 16384 + (size_t)c * 64 + il);
            o0 += bf2f((unsigned short)(pr & 0xffff));
            o1 += bf2f((unsigned short)(pr >> 16));
        }
        o0 *= invL[il];
        o1 *= invL[il + 1];
        size_t gi = (size_t)(b * 256 + c) * 4096 + i0 + il;
        float2v av = *(const float2v*)(a_p + gi);
        float cd0 = cdl[il], cd1 = cdl[il + 1];
        float2v ov;
        ov[0] = gam * av[0] * cd0 + (1.0f - cd0) * o0;
        ov[1] = gam * av[1] * cd1 + (1.0f - cd1) * o1;
        *(float2v*)(out + gi) = ov;
    }
}

// ---------------------------------------------------------------------------
extern "C" void kernel_launch(void* const* d_in, const int* in_sizes, int n_in,
                              void* d_out, int out_size, void* d_ws, size_t ws_size,
                              hipStream_t stream)
{
    const float* a_p   = (const float*)d_in[0];
    const float* b_p   = (const float*)d_in[1];
    const float* c_p   = (const float*)d_in[2];
    const float* wq    = (const float*)d_in[3];
    const float* bq    = (const float*)d_in[4];
    const float* wk    = (const float*)d_in[5];
    const float* bk    = (const float*)d_in[6];
    const float* wv    = (const float*)d_in[7];
    const float* bv    = (const float*)d_in[8];
    const float* gamma = (const float*)d_in[9];
    float* out = (float*)d_out;

    // workspace layout (ushort elems unless noted):
    // Qg 524288 | Kg 524288 | Vg 4194304 | Wbf 81920 | Opart 16777216 | lsum 65536 f32
    unsigned short* Qg    = (unsigned short*)d_ws;
    unsigned short* Kg    = Qg + (size_t)4 * 4096 * 32;
    unsigned short* Vg    = Kg + (size_t)4 * 4096 * 32;
    unsigned short* Wbf   = Vg + (size_t)4 * 256 * 4096;
    unsigned short* Opart = Wbf + (size_t)320 * 256;
    float*          lsum  = (float*)(Opart + (size_t)1024 * 16384);

    wcvt_kernel<<<80, 256, 0, stream>>>(wq, wk, wv, Wbf);
    proj_kernel<<<1024, 256, 0, stream>>>(a_p, b_p, c_p, bq, bk, bv, Wbf, Qg, Kg, Vg);
    attn_kernel<<<1024, 256, 0, stream>>>(Qg, Kg, Vg, Opart, lsum);
    combine_kernel<<<2048, 256, 0, stream>>>(a_p, c_p, gamma, Opart, lsum, out);
}

// Round 8
// 197.249 us; speedup vs baseline: 1.1589x; 1.1589x over previous
//
#include <hip/hip_runtime.h>

#define LOG2E 1.44269504088896340736f

typedef __attribute__((ext_vector_type(8))) short short8;
typedef __attribute__((ext_vector_type(4))) float float4v;
typedef __attribute__((ext_vector_type(2))) float float2v;
typedef __attribute__((ext_vector_type(2))) int int2v;

__device__ inline unsigned short f2bf(float f) {
    union { float f; unsigned u; } v; v.f = f;
    unsigned r = v.u + 0x7fffu + ((v.u >> 16) & 1u);
    return (unsigned short)(r >> 16);
}
__device__ inline float bf2f(unsigned short u) {
    union { unsigned u; float f; } v; v.u = ((unsigned)u) << 16;
    return v.f;
}
// pack hi16(a)|hi16(b)<<16 with +0x8000 rounding (2 adds + 1 perm)
__device__ inline unsigned pk_bf16(float a, float b) {
    union { float f; unsigned u; } ua, ub; ua.f = a; ub.f = b;
    return __builtin_amdgcn_perm(ub.u + 0x8000u, ua.u + 0x8000u, 0x07060302u);
}

// ---------------------------------------------------------------------------
// Kernel 0: convert weights to bf16, concatenated Wbf[320][256]
// rows 0-31 = wq, 32-63 = wk, 64-319 = wv.  grid 80 x 256.
// ---------------------------------------------------------------------------
__global__ void wcvt_kernel(const float* __restrict__ wq, const float* __restrict__ wk,
                            const float* __restrict__ wv, unsigned short* __restrict__ Wbf)
{
    int idx = blockIdx.x * 256 + threadIdx.x;     // 20480 float4s
    int e4  = idx * 4;
    int row = e4 >> 8, col = e4 & 255;
    const float* src = (row < 32) ? (wq + row * 256 + col)
                     : (row < 64) ? (wk + (row - 32) * 256 + col)
                                  : (wv + (row - 64) * 256 + col);
    float4v v = *(const float4v*)src;
    int2v p;
    p.x = (unsigned)f2bf(v[0]) | ((unsigned)f2bf(v[1]) << 16);
    p.y = (unsigned)f2bf(v[2]) | ((unsigned)f2bf(v[3]) << 16);
    *(int2v*)(Wbf + e4) = p;
}

// ---------------------------------------------------------------------------
// Kernel 1: projections.  16-pixel i-tiles, grid 1024 (b = blk&3), block 256.
// Q stored (N,32) bf16 PRE-SCALED by cd[i]*log2(e)  (fixed-max softmax fold).
// K stored (N,32) bf16.
// V stored [b][jblk=i>>5][c][p] bf16, p = ((j&15)>>2)*8 + (j>>4)*4 + (j&3)
// — the k-order of attn's PV MFMA A-fragment (verified R5/R6: passed).
// ---------------------------------------------------------------------------
__launch_bounds__(256, 3)
__global__ void proj_kernel(const float* __restrict__ a_p, const float* __restrict__ b_p,
                            const float* __restrict__ c_p,
                            const float* __restrict__ bq, const float* __restrict__ bk,
                            const float* __restrict__ bv,
                            const unsigned short* __restrict__ Wbf,
                            unsigned short* __restrict__ Qg, unsigned short* __restrict__ Kg,
                            unsigned short* __restrict__ Vg)
{
    __shared__ unsigned At[16 * 132];   // a-tile transposed (i, c-pairs) bf16x2
    __shared__ unsigned Bt[16 * 132];

    const int t    = threadIdx.x;
    const int blk  = blockIdx.x;
    const int b    = blk & 3;
    const int t16  = blk >> 2;
    const int i0   = t16 * 16;
    const int lane = t & 63;
    const int w    = t >> 6;
    const int q    = lane >> 4;
    const int n    = lane & 15;

    // ---- stage: 2 c-rows per thread, two half-passes (16 live regs max) ----
    {
        int arr = t >> 7, p = t & 127;
        const float* src = (arr ? b_p : a_p) + ((size_t)(b * 256 + 2 * p)) * 4096 + i0;
        unsigned* dst = (arr ? Bt : At) + p;
#pragma unroll
        for (int h = 0; h < 2; ++h) {
            float4v r0a = *(const float4v*)(src + h * 8);
            float4v r0b = *(const float4v*)(src + h * 8 + 4);
            float4v r1a = *(const float4v*)(src + 4096 + h * 8);
            float4v r1b = *(const float4v*)(src + 4096 + h * 8 + 4);
#pragma unroll
            for (int jj = 0; jj < 4; ++jj)
                dst[(h * 8 + jj) * 132] = (unsigned)f2bf(r0a[jj]) | ((unsigned)f2bf(r1a[jj]) << 16);
#pragma unroll
            for (int jj = 0; jj < 4; ++jj)
                dst[(h * 8 + 4 + jj) * 132] = (unsigned)f2bf(r0b[jj]) | ((unsigned)f2bf(r1b[jj]) << 16);
        }
    }
    __syncthreads();

    // ---- GEMM: wave w owns m-tiles {w, w+4, w+8, w+12, w+16} (rows of Wbf) ----
    float4v acc[5];
#pragma unroll
    for (int kk = 0; kk < 5; ++kk) acc[kk] = (float4v){0.f, 0.f, 0.f, 0.f};

#pragma unroll 2
    for (int kc = 0; kc < 8; ++kc) {
        short8 atf = *(const short8*)((const unsigned short*)At + n * 264 + kc * 32 + q * 8);
        short8 btf = atf;
        if (w >= 2)  // only waves 2,3 own a K m-tile
            btf = *(const short8*)((const unsigned short*)Bt + n * 264 + kc * 32 + q * 8);
#pragma unroll
        for (int kk = 0; kk < 5; ++kk) {
            int mt = w + 4 * kk;
            short8 wf = *(const short8*)(Wbf + (size_t)(mt * 16 + n) * 256 + kc * 32 + q * 8);
            short8 bsel = (mt == 2 || mt == 3) ? btf : atf;
            acc[kk] = __builtin_amdgcn_mfma_f32_16x16x32_bf16(wf, bsel, acc[kk], 0, 0, 0);
        }
    }

    // ---- store (C-layout: row m = mt*16+q*4+r, col i = i0+n) ----
    const int i = i0 + n;
    const int jj = i & 31;
    const int pperm = ((jj & 15) >> 2) * 8 + (jj >> 4) * 4 + (jj & 3);
    // cd for this pixel (down-sampled c), pre-multiplied by log2(e): folded into Q
    const float cdq = c_p[b * 16384 + (i >> 6) * 256 + (i & 63) * 2] * LOG2E;
#pragma unroll
    for (int kk = 0; kk < 5; ++kk) {
        int mt = w + 4 * kk;
#pragma unroll
        for (int r = 0; r < 4; ++r) {
            int mm = mt * 16 + q * 4 + r;
            float bias = (mm < 32) ? bq[mm] : (mm < 64) ? bk[mm - 32] : bv[mm - 64];
            float val = acc[kk][r] + bias;
            if (mm < 32) {
                Qg[(size_t)(b * 4096 + i) * 32 + mm] = f2bf(val * cdq);
            } else if (mm < 64) {
                Kg[(size_t)(b * 4096 + i) * 32 + (mm - 32)] = f2bf(val);
            } else {
                Vg[(size_t)(((b * 128 + (i >> 5)) * 256) + (mm - 64)) * 32 + pperm] = f2bf(val);
            }
        }
    }
}

// ---------------------------------------------------------------------------
// Kernel 2: flash attention, split-j, fixed-max softmax.  NO LDS, NO barriers.
// R6 structure (c-split: wave w owns channels [64w,64w+64), all 64 rows,
// 4x-redundant S — best measured: 73.6 us) + two cache fixes:
//  (1) XCD swizzle: physical blk = b + 4*(s&1) + 8*(rt + 64*(s>>1)) so each
//      XCD (blk%8) serves ONE batch and 2 of 4 j-splits -> L2-resident V.
//  (2) non-temporal Opart stores: 32 MB of streaming writes no longer evict
//      V from L2 (R6's V re-reads were falling to L3 at ~12 TB/s).
// ---------------------------------------------------------------------------
__launch_bounds__(256, 3)
__global__ void attn_kernel(const unsigned short* __restrict__ Qg,
                            const unsigned short* __restrict__ Kg,
                            const unsigned short* __restrict__ Vg,
                            unsigned short* __restrict__ Opart, float* __restrict__ lsum)
{
    const int t    = threadIdx.x;
    const int blk  = blockIdx.x;
    // swizzled decode: XCD = blk%8 -> (b, s&1) fixed per XCD
    const int b    = blk & 3;
    const int s_lo = (blk >> 2) & 1;
    const int rt   = (blk >> 3) & 63;
    const int s    = s_lo + 2 * (blk >> 9);
    const int lidx = (s << 8) | (rt << 2) | b;    // logical index for Opart/lsum
    const int i0   = rt * 64;
    const int lane = t & 63;
    const int w    = t >> 6;
    const int q    = lane >> 4;
    const int n    = lane & 15;

    // Q B-frags for all 4 i-tiles (every wave computes all 64 rows' S)
    short8 qf[4];
#pragma unroll
    for (int ig = 0; ig < 4; ++ig)
        qf[ig] = *(const short8*)(Qg + (size_t)(b * 4096 + i0 + ig * 16 + n) * 32 + q * 8);

    float4v acc[4][4];   // [ig][ct]
#pragma unroll
    for (int ig = 0; ig < 4; ++ig)
#pragma unroll
        for (int ct = 0; ct < 4; ++ct) acc[ig][ct] = (float4v){0.f, 0.f, 0.f, 0.f};
    float lsc[4] = {0.f, 0.f, 0.f, 0.f};

    const float4v m16v = (float4v){-16.f, -16.f, -16.f, -16.f};

    const unsigned short* kb = Kg + (size_t)(b * 4096 + s * 1024 + n) * 32 + q * 8;
    // wave's own 64-c V slice: [b][jblk][c][p], c = 64w + ct*16 + n, p = q*8..+8
    const unsigned short* vb = Vg + ((size_t)((b * 128 + s * 32) * 256 + w * 64 + n)) * 32 + q * 8;

    short8 kf0 = *(const short8*)(kb);
    short8 kf1 = *(const short8*)(kb + 512);

#pragma unroll 1
    for (int it = 0; it < 32; ++it) {
        // V for this iter (4 KB/wave) — issued a full S-phase ahead of use
        short8 vf[4];
#pragma unroll
        for (int ct = 0; ct < 4; ++ct)
            vf[ct] = *(const short8*)(vb + ct * 512);

        // S^T + exp2 + pack, per i-tile (keeps sv live-range at 8 regs)
        short8 pf[4];
#pragma unroll
        for (int ig = 0; ig < 4; ++ig) {
            float4v s0 = __builtin_amdgcn_mfma_f32_16x16x32_bf16(kf0, qf[ig], m16v, 0, 0, 0);
            float4v s1 = __builtin_amdgcn_mfma_f32_16x16x32_bf16(kf1, qf[ig], m16v, 0, 0, 0);
            float p0 = __builtin_amdgcn_exp2f(s0[0]), p1 = __builtin_amdgcn_exp2f(s0[1]);
            float p2 = __builtin_amdgcn_exp2f(s0[2]), p3 = __builtin_amdgcn_exp2f(s0[3]);
            float p4 = __builtin_amdgcn_exp2f(s1[0]), p5 = __builtin_amdgcn_exp2f(s1[1]);
            float p6 = __builtin_amdgcn_exp2f(s1[2]), p7 = __builtin_amdgcn_exp2f(s1[3]);
            lsc[ig] += ((p0 + p1) + (p2 + p3)) + ((p4 + p5) + (p6 + p7));
            union { short8 s8; unsigned u[4]; } pf_;
            pf_.u[0] = pk_bf16(p0, p1);   // k = jt*4 + r order (matches V perm)
            pf_.u[1] = pk_bf16(p2, p3);
            pf_.u[2] = pk_bf16(p4, p5);
            pf_.u[3] = pk_bf16(p6, p7);
            pf[ig] = pf_.s8;
        }

        // prefetch next iter's K while PV MFMAs run (last iter reads into Vg:
        // in-bounds workspace, unused)
        kf0 = *(const short8*)(kb + 1024);
        kf1 = *(const short8*)(kb + 1536);

#pragma unroll
        for (int ig = 0; ig < 4; ++ig)
#pragma unroll
            for (int ct = 0; ct < 4; ++ct)
                acc[ig][ct] = __builtin_amdgcn_mfma_f32_16x16x32_bf16(pf[ig], vf[ct], acc[ig][ct], 0, 0, 0);

        kb += 1024;    // 32 j-rows * 32
        vb += 8192;    // next jblk: 256 c * 32
    }

    // ---- epilogue: O partial (bf16, unnormalized, NON-TEMPORAL) + l per row ----
    const size_t obase = (size_t)lidx * 16384;
#pragma unroll
    for (int ig = 0; ig < 4; ++ig)
#pragma unroll
        for (int ct = 0; ct < 4; ++ct) {
            int c = w * 64 + ct * 16 + n;
            int i = ig * 16 + q * 4;
            unsigned long long pk =
                (unsigned long long)pk_bf16(acc[ig][ct][0], acc[ig][ct][1]) |
                ((unsigned long long)pk_bf16(acc[ig][ct][2], acc[ig][ct][3]) << 32);
            __builtin_nontemporal_store(pk,
                (unsigned long long*)(Opart + obase + (size_t)c * 64 + i));
        }
    // row sums: reduce over the 4 q-lanes; identical in all 4 waves -> w==0 stores
#pragma unroll
    for (int ig = 0; ig < 4; ++ig) {
        float v = lsc[ig];
        v += __shfl_xor(v, 16, 64);
        v += __shfl_xor(v, 32, 64);
        if (w == 0 && lane < 16)
            lsum[(size_t)lidx * 64 + ig * 16 + lane] = v;
    }
}

// ---------------------------------------------------------------------------
// Kernel 3: combine 4 splits + residual.  grid 2048: b=blk&3, rt=(blk>>2)&63,
// cs=blk>>8 (8 c-slices of 32).  out = gam*a*cd + (1-cd) * (sum_s O_s)/(sum_s l_s)
// ---------------------------------------------------------------------------
__launch_bounds__(256, 4)
__global__ void combine_kernel(const float* __restrict__ a_p, const float* __restrict__ c_p,
                               const float* __restrict__ gamma_p,
                               const unsigned short* __restrict__ Opart,
                               const float* __restrict__ lsum, float* __restrict__ out)
{
    __shared__ float invL[64];
    __shared__ float cdl[64];

    const int t   = threadIdx.x;
    const int blk = blockIdx.x;
    const int b   = blk & 3;
    const int rt  = (blk >> 2) & 63;
    const int cs  = blk >> 8;
    const int i0  = rt * 64;

    if (t < 64) {
        float L = 0.f;
#pragma unroll
        for (int s = 0; s < 4; ++s)
            L += lsum[(size_t)((s << 8) | (rt << 2) | b) * 64 + t];
        invL[t] = 1.0f / L;
        cdl[t] = c_p[b * 16384 + rt * 256 + 2 * t];
    }
    __syncthreads();

    const float gam = gamma_p[0];
    const int il = (t & 31) * 2;
    const int cq = t >> 5;
#pragma unroll
    for (int k = 0; k < 4; ++k) {
        int c = cs * 32 + cq + 8 * k;
        float o0 = 0.f, o1 = 0.f;
#pragma unroll
        for (int s = 0; s < 4; ++s) {
            int idx = (s << 8) | (rt << 2) | b;
            unsigned pr = *(const unsigned*)(Opart + (size_t)idx * 16384 + (size_t)c * 64 + il);
            o0 += bf2f((unsigned short)(pr & 0xffff));
            o1 += bf2f((unsigned short)(pr >> 16));
        }
        o0 *= invL[il];
        o1 *= invL[il + 1];
        size_t gi = (size_t)(b * 256 + c) * 4096 + i0 + il;
        float2v av = *(const float2v*)(a_p + gi);
        float cd0 = cdl[il], cd1 = cdl[il + 1];
        float2v ov;
        ov[0] = gam * av[0] * cd0 + (1.0f - cd0) * o0;
        ov[1] = gam * av[1] * cd1 + (1.0f - cd1) * o1;
        *(float2v*)(out + gi) = ov;
    }
}

// ---------------------------------------------------------------------------
extern "C" void kernel_launch(void* const* d_in, const int* in_sizes, int n_in,
                              void* d_out, int out_size, void* d_ws, size_t ws_size,
                              hipStream_t stream)
{
    const float* a_p   = (const float*)d_in[0];
    const float* b_p   = (const float*)d_in[1];
    const float* c_p   = (const float*)d_in[2];
    const float* wq    = (const float*)d_in[3];
    const float* bq    = (const float*)d_in[4];
    const float* wk    = (const float*)d_in[5];
    const float* bk    = (const float*)d_in[6];
    const float* wv    = (const float*)d_in[7];
    const float* bv    = (const float*)d_in[8];
    const float* gamma = (const float*)d_in[9];
    float* out = (float*)d_out;

    // workspace layout (ushort elems unless noted):
    // Qg 524288 | Kg 524288 | Vg 4194304 | Wbf 81920 | Opart 16777216 | lsum 65536 f32
    unsigned short* Qg    = (unsigned short*)d_ws;
    unsigned short* Kg    = Qg + (size_t)4 * 4096 * 32;
    unsigned short* Vg    = Kg + (size_t)4 * 4096 * 32;
    unsigned short* Wbf   = Vg + (size_t)4 * 256 * 4096;
    unsigned short* Opart = Wbf + (size_t)320 * 256;
    float*          lsum  = (float*)(Opart + (size_t)1024 * 16384);

    wcvt_kernel<<<80, 256, 0, stream>>>(wq, wk, wv, Wbf);
    proj_kernel<<<1024, 256, 0, stream>>>(a_p, b_p, c_p, bq, bk, bv, Wbf, Qg, Kg, Vg);
    attn_kernel<<<1024, 256, 0, stream>>>(Qg, Kg, Vg, Opart, lsum);
    combine_kernel<<<2048, 256, 0, stream>>>(a_p, c_p, gamma, Opart, lsum, out);
}

// Round 9
// 188.455 us; speedup vs baseline: 1.2130x; 1.0467x over previous
//
#include <hip/hip_runtime.h>

#define LOG2E 1.44269504088896340736f

typedef __attribute__((ext_vector_type(8))) short short8;
typedef __attribute__((ext_vector_type(4))) float float4v;
typedef __attribute__((ext_vector_type(2))) float float2v;
typedef __attribute__((ext_vector_type(2))) int int2v;
typedef __attribute__((ext_vector_type(4))) int int4v;

__device__ inline unsigned short f2bf(float f) {
    union { float f; unsigned u; } v; v.f = f;
    unsigned r = v.u + 0x7fffu + ((v.u >> 16) & 1u);
    return (unsigned short)(r >> 16);
}
__device__ inline float bf2f(unsigned short u) {
    union { unsigned u; float f; } v; v.u = ((unsigned)u) << 16;
    return v.f;
}
// pack hi16(a)|hi16(b)<<16 with +0x8000 rounding (2 adds + 1 perm); a = low half
__device__ inline unsigned pk_bf16(float a, float b) {
    union { float f; unsigned u; } ua, ub; ua.f = a; ub.f = b;
    return __builtin_amdgcn_perm(ub.u + 0x8000u, ua.u + 0x8000u, 0x07060302u);
}

// ---------------------------------------------------------------------------
// Kernel 0: convert weights to bf16, concatenated Wbf[320][256]
// rows 0-31 = wq, 32-63 = wk, 64-319 = wv.  grid 80 x 256.
// ---------------------------------------------------------------------------
__global__ void wcvt_kernel(const float* __restrict__ wq, const float* __restrict__ wk,
                            const float* __restrict__ wv, unsigned short* __restrict__ Wbf)
{
    int idx = blockIdx.x * 256 + threadIdx.x;     // 20480 float4s
    int e4  = idx * 4;
    int row = e4 >> 8, col = e4 & 255;
    const float* src = (row < 32) ? (wq + row * 256 + col)
                     : (row < 64) ? (wk + (row - 32) * 256 + col)
                                  : (wv + (row - 64) * 256 + col);
    float4v v = *(const float4v*)src;
    int2v p;
    p.x = (unsigned)f2bf(v[0]) | ((unsigned)f2bf(v[1]) << 16);
    p.y = (unsigned)f2bf(v[2]) | ((unsigned)f2bf(v[3]) << 16);
    *(int2v*)(Wbf + e4) = p;
}

// ---------------------------------------------------------------------------
// Kernel 1: projections v2 — 64-pixel tiles, grid 256 (b=blk&3, tile=blk>>2),
// block 512 (8 waves).  Three phases:
//  (1) stage a,b tiles transposed to LDS (i, c) bf16;
//  (2) MFMA (A = Wbf rows, B = X^T): wave w owns i-tile (w&3) and m-tiles
//      [10*(w>>2), +10) of the 20 (0,1=Q; 2,3=K; 4..19=V);
//  (3) frags -> LDS staging (over At/Bt), then COALESCED 16B/lane global
//      writes (old proj used 2B scattered stores — the hidden ~90 us).
// Q pre-scaled by cd[i]*log2e; V layout [b][jblk][c][p],
// p = ((j&15)>>2)*8 + ((j>>4)&1)*4 + (j&3)   (verified R5-R8).
// ---------------------------------------------------------------------------
__launch_bounds__(512, 2)
__global__ void proj_kernel(const float* __restrict__ a_p, const float* __restrict__ b_p,
                            const float* __restrict__ c_p,
                            const float* __restrict__ bq, const float* __restrict__ bk,
                            const float* __restrict__ bv,
                            const unsigned short* __restrict__ Wbf,
                            unsigned short* __restrict__ Qg, unsigned short* __restrict__ Kg,
                            unsigned short* __restrict__ Vg)
{
    __shared__ __align__(16) unsigned short At[64 * 264];   // (i, c) bf16, pad 264
    __shared__ __align__(16) unsigned short Bt[64 * 264];
    __shared__ float bias[320];
    __shared__ float cdl[64];

    const int t    = threadIdx.x;
    const int blk  = blockIdx.x;
    const int b    = blk & 3;
    const int tile = blk >> 2;
    const int i0   = tile * 64;
    const int lane = t & 63;
    const int w    = t >> 6;
    const int q    = lane >> 4;
    const int n    = lane & 15;
    const int it   = w & 3;     // i-tile
    const int mh   = w >> 2;    // m-half (0: mt 0-9, 1: mt 10-19)

    // ---- phase 1: stage inputs.  thread: arr=t>>8, c-pair cp=(t>>1)&127,
    // i-half ih=(t&1)*32; 4 chunks of 8 px; packed b32 writes (c-pair). ----
    {
        const int arr = t >> 8, cp = (t >> 1) & 127, ih = (t & 1) * 32;
        const float* src = (arr ? b_p : a_p) + ((size_t)(b * 256 + 2 * cp)) * 4096 + i0 + ih;
        unsigned* dst = (unsigned*)(arr ? Bt : At) + cp;   // uint cols = 132
#pragma unroll
        for (int h = 0; h < 4; ++h) {
            float4v r0a = *(const float4v*)(src + h * 8);
            float4v r0b = *(const float4v*)(src + h * 8 + 4);
            float4v r1a = *(const float4v*)(src + 4096 + h * 8);
            float4v r1b = *(const float4v*)(src + 4096 + h * 8 + 4);
#pragma unroll
            for (int jj = 0; jj < 4; ++jj)
                dst[(ih + h * 8 + jj) * 132] = pk_bf16(r0a[jj], r1a[jj]);
#pragma unroll
            for (int jj = 0; jj < 4; ++jj)
                dst[(ih + h * 8 + 4 + jj) * 132] = pk_bf16(r0b[jj], r1b[jj]);
        }
        if (t < 320) bias[t] = (t < 32) ? bq[t] : (t < 64) ? bk[t - 32] : bv[t - 64];
        else if (t < 384) cdl[t - 320] = c_p[b * 16384 + tile * 256 + (t - 320) * 2];
    }
    __syncthreads();

    // ---- phase 2: MFMA ----
    float4v acc[10];
#pragma unroll
    for (int j = 0; j < 10; ++j) acc[j] = (float4v){0.f, 0.f, 0.f, 0.f};

#pragma unroll 2
    for (int kc = 0; kc < 8; ++kc) {
        short8 xa = *(const short8*)&At[(it * 16 + n) * 264 + kc * 32 + q * 8];
        short8 xb = xa;
        if (mh == 0)
            xb = *(const short8*)&Bt[(it * 16 + n) * 264 + kc * 32 + q * 8];
#pragma unroll
        for (int j = 0; j < 10; ++j) {
            int mt = mh * 10 + j;
            short8 wf = *(const short8*)(Wbf + (size_t)(mt * 16 + n) * 256 + kc * 32 + q * 8);
            short8 bsel = (mt == 2 || mt == 3) ? xb : xa;
            acc[j] = __builtin_amdgcn_mfma_f32_16x16x32_bf16(wf, bsel, acc[j], 0, 0, 0);
        }
    }
    __syncthreads();   // all LDS reads done; At/Bt reusable as staging

    // ---- phase 3a: frags -> LDS staging ----
    unsigned short* QKst = At;   // [i][72] ushort (row 144B, 16B-aligned)
    unsigned short* Vst  = Bt;   // [jb][c][32] ushort = 16384
    {
        const float cdq = cdl[it * 16 + n] * LOG2E;
#pragma unroll
        for (int j = 0; j < 10; ++j) {
            int mt = mh * 10 + j;
            float4v bv4 = *(const float4v*)&bias[mt * 16 + q * 4];
            float v0 = acc[j][0] + bv4[0], v1 = acc[j][1] + bv4[1];
            float v2 = acc[j][2] + bv4[2], v3 = acc[j][3] + bv4[3];
            if (mt < 2) {        // Q: scale by cd*log2e, rows m = mt*16+q*4+r
                v0 *= cdq; v1 *= cdq; v2 *= cdq; v3 *= cdq;
                int2v pk; pk.x = (int)pk_bf16(v0, v1); pk.y = (int)pk_bf16(v2, v3);
                *(int2v*)&QKst[(it * 16 + n) * 72 + mt * 16 + q * 4] = pk;
            } else if (mt < 4) { // K
                int2v pk; pk.x = (int)pk_bf16(v0, v1); pk.y = (int)pk_bf16(v2, v3);
                *(int2v*)&QKst[(it * 16 + n) * 72 + mt * 16 + q * 4] = pk;
            } else {             // V: c = mt*16-64+q*4+r, p fixed per lane
                int p = ((n >> 2) * 8) + ((it & 1) * 4) + (n & 3);
                int cbase = mt * 16 - 64 + q * 4;
                int jb = it >> 1;
                Vst[((jb * 256) + cbase + 0) * 32 + p] = f2bf(v0);
                Vst[((jb * 256) + cbase + 1) * 32 + p] = f2bf(v1);
                Vst[((jb * 256) + cbase + 2) * 32 + p] = f2bf(v2);
                Vst[((jb * 256) + cbase + 3) * 32 + p] = f2bf(v3);
            }
        }
    }
    __syncthreads();

    // ---- phase 3b: coalesced global writes (16B per lane) ----
    {   // Q/K: 64 i x 64 m; thread: i = t>>3, 8-m chunk h8 = t&7
        int i = t >> 3, h8 = t & 7;
        int4v v = *(const int4v*)&QKst[i * 72 + h8 * 8];
        unsigned short* dstp = (h8 < 4)
            ? Qg + (size_t)(b * 4096 + i0 + i) * 32 + h8 * 8
            : Kg + (size_t)(b * 4096 + i0 + i) * 32 + (h8 - 4) * 8;
        *(int4v*)dstp = v;
    }
    {   // V: 32KB flat copy (Vst inner layout == Vg inner layout)
#pragma unroll
        for (int k = 0; k < 4; ++k) {
            int flat = k * 512 + t;              // 16B units
            int4v v = *(const int4v*)&Vst[flat * 8];
            int jb = flat >> 10;                 // 1024 x 16B per jblk
            *(int4v*)(Vg + (size_t)(b * 128 + tile * 2 + jb) * 8192 + (flat & 1023) * 8) = v;
        }
    }
}

// ---------------------------------------------------------------------------
// Kernel 2: flash attention, split-j, fixed-max softmax.  NO LDS, NO barriers.
// R6 c-split structure + R8 XCD swizzle (keeps FETCH halved).  Plain stores
// (R8's non-temporal store doubled HBM WRITE for zero gain — reverted).
// ---------------------------------------------------------------------------
__launch_bounds__(256, 3)
__global__ void attn_kernel(const unsigned short* __restrict__ Qg,
                            const unsigned short* __restrict__ Kg,
                            const unsigned short* __restrict__ Vg,
                            unsigned short* __restrict__ Opart, float* __restrict__ lsum)
{
    const int t    = threadIdx.x;
    const int blk  = blockIdx.x;
    // swizzled decode: XCD = blk%8 -> (b, s&1) fixed per XCD
    const int b    = blk & 3;
    const int s_lo = (blk >> 2) & 1;
    const int rt   = (blk >> 3) & 63;
    const int s    = s_lo + 2 * (blk >> 9);
    const int lidx = (s << 8) | (rt << 2) | b;    // logical index for Opart/lsum
    const int i0   = rt * 64;
    const int lane = t & 63;
    const int w    = t >> 6;
    const int q    = lane >> 4;
    const int n    = lane & 15;

    // Q B-frags for all 4 i-tiles (every wave computes all 64 rows' S)
    short8 qf[4];
#pragma unroll
    for (int ig = 0; ig < 4; ++ig)
        qf[ig] = *(const short8*)(Qg + (size_t)(b * 4096 + i0 + ig * 16 + n) * 32 + q * 8);

    float4v acc[4][4];   // [ig][ct]
#pragma unroll
    for (int ig = 0; ig < 4; ++ig)
#pragma unroll
        for (int ct = 0; ct < 4; ++ct) acc[ig][ct] = (float4v){0.f, 0.f, 0.f, 0.f};
    float lsc[4] = {0.f, 0.f, 0.f, 0.f};

    const float4v m16v = (float4v){-16.f, -16.f, -16.f, -16.f};

    const unsigned short* kb = Kg + (size_t)(b * 4096 + s * 1024 + n) * 32 + q * 8;
    // wave's own 64-c V slice: [b][jblk][c][p], c = 64w + ct*16 + n, p = q*8..+8
    const unsigned short* vb = Vg + ((size_t)((b * 128 + s * 32) * 256 + w * 64 + n)) * 32 + q * 8;

    short8 kf0 = *(const short8*)(kb);
    short8 kf1 = *(const short8*)(kb + 512);

#pragma unroll 1
    for (int it = 0; it < 32; ++it) {
        // V for this iter (4 KB/wave) — issued a full S-phase ahead of use
        short8 vf[4];
#pragma unroll
        for (int ct = 0; ct < 4; ++ct)
            vf[ct] = *(const short8*)(vb + ct * 512);

        // S^T + exp2 + pack, per i-tile (keeps sv live-range at 8 regs)
        short8 pf[4];
#pragma unroll
        for (int ig = 0; ig < 4; ++ig) {
            float4v s0 = __builtin_amdgcn_mfma_f32_16x16x32_bf16(kf0, qf[ig], m16v, 0, 0, 0);
            float4v s1 = __builtin_amdgcn_mfma_f32_16x16x32_bf16(kf1, qf[ig], m16v, 0, 0, 0);
            float p0 = __builtin_amdgcn_exp2f(s0[0]), p1 = __builtin_amdgcn_exp2f(s0[1]);
            float p2 = __builtin_amdgcn_exp2f(s0[2]), p3 = __builtin_amdgcn_exp2f(s0[3]);
            float p4 = __builtin_amdgcn_exp2f(s1[0]), p5 = __builtin_amdgcn_exp2f(s1[1]);
            float p6 = __builtin_amdgcn_exp2f(s1[2]), p7 = __builtin_amdgcn_exp2f(s1[3]);
            lsc[ig] += ((p0 + p1) + (p2 + p3)) + ((p4 + p5) + (p6 + p7));
            union { short8 s8; unsigned u[4]; } pf_;
            pf_.u[0] = pk_bf16(p0, p1);   // k = jt*4 + r order (matches V perm)
            pf_.u[1] = pk_bf16(p2, p3);
            pf_.u[2] = pk_bf16(p4, p5);
            pf_.u[3] = pk_bf16(p6, p7);
            pf[ig] = pf_.s8;
        }

        // prefetch next iter's K while PV MFMAs run (last iter reads into Vg:
        // in-bounds workspace, unused)
        kf0 = *(const short8*)(kb + 1024);
        kf1 = *(const short8*)(kb + 1536);

#pragma unroll
        for (int ig = 0; ig < 4; ++ig)
#pragma unroll
            for (int ct = 0; ct < 4; ++ct)
                acc[ig][ct] = __builtin_amdgcn_mfma_f32_16x16x32_bf16(pf[ig], vf[ct], acc[ig][ct], 0, 0, 0);

        kb += 1024;    // 32 j-rows * 32
        vb += 8192;    // next jblk: 256 c * 32
    }

    // ---- epilogue: O partial (bf16, unnormalized) + l per row ----
    const size_t obase = (size_t)lidx * 16384;
#pragma unroll
    for (int ig = 0; ig < 4; ++ig)
#pragma unroll
        for (int ct = 0; ct < 4; ++ct) {
            int c = w * 64 + ct * 16 + n;
            int i = ig * 16 + q * 4;
            int2v pk;
            pk.x = (int)pk_bf16(acc[ig][ct][0], acc[ig][ct][1]);
            pk.y = (int)pk_bf16(acc[ig][ct][2], acc[ig][ct][3]);
            *(int2v*)(Opart + obase + (size_t)c * 64 + i) = pk;
        }
    // row sums: reduce over the 4 q-lanes; identical in all 4 waves -> w==0 stores
#pragma unroll
    for (int ig = 0; ig < 4; ++ig) {
        float v = lsc[ig];
        v += __shfl_xor(v, 16, 64);
        v += __shfl_xor(v, 32, 64);
        if (w == 0 && lane < 16)
            lsum[(size_t)lidx * 64 + ig * 16 + lane] = v;
    }
}

// ---------------------------------------------------------------------------
// Kernel 3: combine 4 splits + residual.  grid 2048: b=blk&3, rt=(blk>>2)&63,
// cs=blk>>8 (8 c-slices of 32).  out = gam*a*cd + (1-cd) * (sum_s O_s)/(sum_s l_s)
// ---------------------------------------------------------------------------
__launch_bounds__(256, 4)
__global__ void combine_kernel(const float* __restrict__ a_p, const float* __restrict__ c_p,
                               const float* __restrict__ gamma_p,
                               const unsigned short* __restrict__ Opart,
                               const float* __restrict__ lsum, float* __restrict__ out)
{
    __shared__ float invL[64];
    __shared__ float cdl[64];

    const int t   = threadIdx.x;
    const int blk = blockIdx.x;
    const int b   = blk & 3;
    const int rt  = (blk >> 2) & 63;
    const int cs  = blk >> 8;
    const int i0  = rt * 64;

    if (t < 64) {
        float L = 0.f;
#pragma unroll
        for (int s = 0; s < 4; ++s)
            L += lsum[(size_t)((s << 8) | (rt << 2) | b) * 64 + t];
        invL[t] = 1.0f / L;
        cdl[t] = c_p[b * 16384 + rt * 256 + 2 * t];
    }
    __syncthreads();

    const float gam = gamma_p[0];
    const int il = (t & 31) * 2;
    const int cq = t >> 5;
#pragma unroll
    for (int k = 0; k < 4; ++k) {
        int c = cs * 32 + cq + 8 * k;
        float o0 = 0.f, o1 = 0.f;
#pragma unroll
        for (int s = 0; s < 4; ++s) {
            int idx = (s << 8) | (rt << 2) | b;
            unsigned pr = *(const unsigned*)(Opart + (size_t)idx * 16384 + (size_t)c * 64 + il);
            o0 += bf2f((unsigned short)(pr & 0xffff));
            o1 += bf2f((unsigned short)(pr >> 16));
        }
        o0 *= invL[il];
        o1 *= invL[il + 1];
        size_t gi = (size_t)(b * 256 + c) * 4096 + i0 + il;
        float2v av = *(const float2v*)(a_p + gi);
        float cd0 = cdl[il], cd1 = cdl[il + 1];
        float2v ov;
        ov[0] = gam * av[0] * cd0 + (1.0f - cd0) * o0;
        ov[1] = gam * av[1] * cd1 + (1.0f - cd1) * o1;
        *(float2v*)(out + gi) = ov;
    }
}

// ---------------------------------------------------------------------------
extern "C" void kernel_launch(void* const* d_in, const int* in_sizes, int n_in,
                              void* d_out, int out_size, void* d_ws, size_t ws_size,
                              hipStream_t stream)
{
    const float* a_p   = (const float*)d_in[0];
    const float* b_p   = (const float*)d_in[1];
    const float* c_p   = (const float*)d_in[2];
    const float* wq    = (const float*)d_in[3];
    const float* bq    = (const float*)d_in[4];
    const float* wk    = (const float*)d_in[5];
    const float* bk    = (const float*)d_in[6];
    const float* wv    = (const float*)d_in[7];
    const float* bv    = (const float*)d_in[8];
    const float* gamma = (const float*)d_in[9];
    float* out = (float*)d_out;

    // workspace layout (ushort elems unless noted):
    // Qg 524288 | Kg 524288 | Vg 4194304 | Wbf 81920 | Opart 16777216 | lsum 65536 f32
    unsigned short* Qg    = (unsigned short*)d_ws;
    unsigned short* Kg    = Qg + (size_t)4 * 4096 * 32;
    unsigned short* Vg    = Kg + (size_t)4 * 4096 * 32;
    unsigned short* Wbf   = Vg + (size_t)4 * 256 * 4096;
    unsigned short* Opart = Wbf + (size_t)320 * 256;
    float*          lsum  = (float*)(Opart + (size_t)1024 * 16384);

    wcvt_kernel<<<80, 256, 0, stream>>>(wq, wk, wv, Wbf);
    proj_kernel<<<256, 512, 0, stream>>>(a_p, b_p, c_p, bq, bk, bv, Wbf, Qg, Kg, Vg);
    attn_kernel<<<1024, 256, 0, stream>>>(Qg, Kg, Vg, Opart, lsum);
    combine_kernel<<<2048, 256, 0, stream>>>(a_p, c_p, gamma, Opart, lsum, out);
}